// Round 5
// baseline (244.865 us; speedup 1.0000x reference)
//
#include <hip/hip_runtime.h>
#include <hip/hip_bf16.h>

typedef __bf16 bf16x8 __attribute__((ext_vector_type(8)));
typedef float f32x4 __attribute__((ext_vector_type(4)));

#define NB 16
#define NC 256
#define NHW 3136
#define NW 56
#define PROW 58
#define PPLANE (58 * 58)

#define NRX 12544
#define NRW 2389
#define NHALO 114

__device__ __forceinline__ unsigned short f2bf(float f) {
    union { float f; unsigned u; } v; v.f = f;
    unsigned r = v.u + 0x7FFFu + ((v.u >> 16) & 1u);
    return (unsigned short)(r >> 16);
}

__device__ __forceinline__ void gload_lds16(const void* g, void* l) {
    __builtin_amdgcn_global_load_lds((const __attribute__((address_space(1))) void*)g,
                                     (__attribute__((address_space(3))) void*)l, 16, 0, 0);
}

// ---------- kernel 1: fused prep: repack_x || repack_w || halo-zero ----------
__global__ void k_prep(const float* __restrict__ x,
                       const float* __restrict__ w0_0, const float* __restrict__ w0_1,
                       const float* __restrict__ w0_2, const float* __restrict__ w0_3,
                       const float* __restrict__ w0_4, const float* __restrict__ w1,
                       const float* __restrict__ w2, const float* __restrict__ fc1_w,
                       unsigned short* __restrict__ xT, unsigned short* __restrict__ Bp,
                       float* __restrict__ w01T, float* __restrict__ w02T,
                       float* __restrict__ w03T, float* __restrict__ w04T,
                       float* __restrict__ fc1T, float* __restrict__ w1T,
                       float* __restrict__ w2c) {
    __shared__ float sh[64 * 65];
    int bid = blockIdx.x, tid = threadIdx.x;

    if (bid < NRX) {
        // ---- repack_x: NCHW f32 -> padded channel-blocked bf16 ----
        int hwb = bid % 98;
        int cb = (bid / 98) % 8;
        int b = bid / (98 * 8);
        {
            int c_l = tid >> 5, hw_l = tid & 31;
            const float* src = x + ((size_t)b * NC + (size_t)cb * 32) * NHW + hwb * 32;
#pragma unroll
            for (int r = 0; r < 4; ++r) {
                int c = c_l + r * 8;
                sh[c * 33 + hw_l] = src[(size_t)c * NHW + hw_l];
            }
        }
        __syncthreads();
        {
            int qd = tid & 7, hw2 = tid >> 3;
            int hw = hwb * 32 + hw2;
            int y = hw / 56, xp = hw - y * 56;
            unsigned short* dst = xT + ((size_t)(b * 8 + cb) * PPLANE +
                                        (size_t)(y + 1) * PROW + (xp + 1)) * 32 + qd * 4;
            ushort4 v;
            v.x = f2bf(sh[(qd * 4 + 0) * 33 + hw2]);
            v.y = f2bf(sh[(qd * 4 + 1) * 33 + hw2]);
            v.z = f2bf(sh[(qd * 4 + 2) * 33 + hw2]);
            v.w = f2bf(sh[(qd * 4 + 3) * 33 + hw2]);
            *(ushort4*)dst = v;
        }
        return;
    }
    if (bid < NRX + NRW) {
        int bw = bid - NRX;
        if (bw < 2304) {
            int idx = bw * 256 + tid;
            int q = idx & 31;
            int n = (idx >> 5) & 255;
            int s = idx >> 13;
            int tap = s >> 3;
            int ic = (s & 7) * 32 + q;
            Bp[idx] = f2bf(w0_0[(size_t)n * 2304 + (size_t)ic * 9 + tap]);
            return;
        }
        int tb = bw - 2304;
        if (tb < 84) {
            const float* src; float* dst;
            int sstr, estr, off, OD, o0, i0;
            if (tb < 80) {
                int arr = tb >> 4, t16 = tb & 15;
                o0 = (t16 >> 2) * 64; i0 = (t16 & 3) * 64; OD = 256;
                sstr = 2304; estr = 9; off = 4;
                switch (arr) {
                    case 0: src = w0_1; dst = w01T; break;
                    case 1: src = w0_2; dst = w02T; break;
                    case 2: src = w0_3; dst = w03T; break;
                    case 3: src = w0_4; dst = w04T; break;
                    default: src = fc1_w; dst = fc1T; sstr = 256; estr = 1; off = 0; break;
                }
            } else {
                int t4i = tb - 80; o0 = 0; i0 = t4i * 64; OD = 64;
                sstr = 2304; estr = 9; off = 4;
                src = w1; dst = w1T;
            }
            int i1 = tid & 63, o4 = tid >> 6;
#pragma unroll
            for (int p = 0; p < 16; ++p) {
                int oo = p * 4 + o4;
                sh[oo * 65 + i1] = src[(size_t)(o0 + oo) * sstr + (size_t)(i0 + i1) * estr + off];
            }
            __syncthreads();
            int o1 = tid & 63, i4 = tid >> 6;
#pragma unroll
            for (int p = 0; p < 16; ++p) {
                int ii = p * 4 + i4;
                dst[(size_t)(i0 + ii) * OD + o0 + o1] = sh[o1 * 65 + ii];
            }
        } else {
            if (tid < 64) w2c[tid] = w2[tid * 9 + 4];
        }
        return;
    }
    // ---- halo zero ----
    {
        int t = (bid - NRX - NRW) * 256 + tid;
        if (t >= 128 * 228) return;
        int plane = t / 228, h = t % 228;
        int row, xc;
        if (h < 58)       { row = 0;       xc = h; }
        else if (h < 116) { row = 57;      xc = h - 58; }
        else if (h < 172) { row = h - 115; xc = 0; }
        else              { row = h - 171; xc = 57; }
        size_t e = ((size_t)plane * PPLANE + (size_t)row * PROW + xc) * 32;
        uint4 z = {0u, 0u, 0u, 0u};
        *(uint4*)(xT + e)      = z;
        *(uint4*)(xT + e + 8)  = z;
        *(uint4*)(xT + e + 16) = z;
        *(uint4*)(xT + e + 24) = z;
    }
}

// ---------- kernel 2: implicit-GEMM conv + relu + sum ----------
// grid 896 = b*56 + y (one output row / block); 4 waves, wave owns 64 N cols.
// M = 64 (56 valid), K = 2304. A: 3-row LDS dbuf via global_load_lds
// (swizzled source, linear dest); B direct from L2.
__global__ __launch_bounds__(256, 3) void k_conv(
    const unsigned short* __restrict__ xT,
    const unsigned short* __restrict__ Bp,
    const float* __restrict__ b0_0,
    float* __restrict__ partial) {
    __shared__ __align__(16) char alds[2][12288];   // [buf][3 rows][64 px][64B]
    int blk = blockIdx.x;
    int b = blk / 56, y = blk % 56;
    int tid = threadIdx.x;
    int lane = tid & 63, wave = tid >> 6;
    int col = lane & 15, grp = lane >> 4;
    int nbase = wave * 64;

    // staging descriptors: 3 rounds of 256 chunks; chunk c<696 = (row, px, part)
    int g_off[3]; bool g_act[3];
#pragma unroll
    for (int r = 0; r < 3; ++r) {
        int c = r * 256 + tid;
        int row = c / 232, rem = c - row * 232;
        int px = rem >> 2, part = rem & 3;
        g_act[r] = (c < 696);
        g_off[r] = ((y + row) * PROW + px) * 64 + ((part ^ ((px >> 1) & 3)) << 4);
    }

    // read-side LDS offsets (slot-swizzled, clamped: m>=56 discarded anyway)
    int p_[4][3];
#pragma unroll
    for (int mt = 0; mt < 4; ++mt) {
        int q = mt * 16 + col;
#pragma unroll
        for (int dxi = 0; dxi < 3; ++dxi) {
            int ppx = q + dxi;
            if (ppx > 63) ppx = 63;
            int slot = grp ^ ((ppx >> 1) & 3);
            p_[mt][dxi] = ppx * 64 + slot * 16;
        }
    }
    int boff[4];
#pragma unroll
    for (int nt = 0; nt < 4; ++nt)
        boff[nt] = ((nbase + nt * 16 + col) * 32 + grp * 8) * 2;

    f32x4 acc[4][4];
#pragma unroll
    for (int mt = 0; mt < 4; ++mt)
#pragma unroll
        for (int nt = 0; nt < 4; ++nt) {
            acc[mt][nt][0] = 0.f; acc[mt][nt][1] = 0.f;
            acc[mt][nt][2] = 0.f; acc[mt][nt][3] = 0.f;
        }

    const char* xbytes = (const char*)xT;
    // prologue: stage icb=0 into buf0
    {
        const char* gp = xbytes + (size_t)(b * 8) * (PPLANE * 64);
#pragma unroll
        for (int r = 0; r < 3; ++r)
            if (g_act[r]) gload_lds16(gp + g_off[r], &alds[0][r * 4096 + wave * 1024]);
    }
    __syncthreads();

    for (int icb = 0; icb < 8; ++icb) {
        int cur = icb & 1;
        if (icb < 7) {
            const char* gp = xbytes + (size_t)(b * 8 + icb + 1) * (PPLANE * 64);
#pragma unroll
            for (int r = 0; r < 3; ++r)
                if (g_act[r]) gload_lds16(gp + g_off[r], &alds[cur ^ 1][r * 4096 + wave * 1024]);
        }
        const char* abuf = alds[cur];
#pragma unroll
        for (int dyi = 0; dyi < 3; ++dyi) {
#pragma unroll
            for (int dxi = 0; dxi < 3; ++dxi) {
                int tap = dyi * 3 + dxi;
                const char* bplane = (const char*)(Bp + ((size_t)(tap * 8 + icb) << 13));
                bf16x8 af[4], bfr[4];
#pragma unroll
                for (int nt = 0; nt < 4; ++nt)
                    bfr[nt] = *(const bf16x8*)(bplane + boff[nt]);
#pragma unroll
                for (int mt = 0; mt < 4; ++mt)
                    af[mt] = *(const bf16x8*)(abuf + (dyi * 4096 + p_[mt][dxi]));
#pragma unroll
                for (int mt = 0; mt < 4; ++mt)
#pragma unroll
                    for (int nt = 0; nt < 4; ++nt)
                        acc[mt][nt] = __builtin_amdgcn_mfma_f32_16x16x32_bf16(af[mt], bfr[nt], acc[mt][nt], 0, 0, 0);
            }
        }
        __syncthreads();
    }

    // epilogue: bias + relu + sum over valid m (<56)
#pragma unroll
    for (int nt = 0; nt < 4; ++nt) {
        int n = nbase + nt * 16 + col;
        float bias = b0_0[n];
        float s = 0.f;
#pragma unroll
        for (int mt = 0; mt < 4; ++mt)
#pragma unroll
            for (int j = 0; j < 4; ++j) {
                int m = mt * 16 + grp * 4 + j;
                if (m < NW) s += fmaxf(acc[mt][nt][j] + bias, 0.f);
            }
        s += __shfl_down(s, 32);
        s += __shfl_down(s, 16);
        if (grp == 0) partial[((size_t)b * NW + y) * NC + n] = s;
    }
}

// ---------- kernel 3: tail, 1024 threads, 4-way K-split matvecs ----------
__global__ __launch_bounds__(1024) void k_tail(
    const float* __restrict__ partial,
    const float* __restrict__ w01T, const float* __restrict__ fc1T,
    const float* __restrict__ w02T, const float* __restrict__ w03T,
    const float* __restrict__ w04T, const float* __restrict__ w1T,
    const float* __restrict__ w2c,
    const float* __restrict__ b0_1, const float* __restrict__ b0_2,
    const float* __restrict__ b0_3, const float* __restrict__ b0_4,
    const float* __restrict__ b1, const float* __restrict__ b2,
    const float* __restrict__ fc2_w, const float* __restrict__ fc2_b,
    const float* __restrict__ compat, const float* __restrict__ spatial_w,
    float* __restrict__ out) {
    __shared__ float fc[256], t2[256], t3[256], t4[256];
    __shared__ float rA[4][256], rB[4][256];
    __shared__ float red64[64];
    __shared__ float vs_sh;
    int b = blockIdx.x, tid = threadIdx.x;
    int o = tid & 255, seg = tid >> 8;
    int i0 = seg * 64;

    // f1c mean: 56 per-row partials, 14 per seg
    {
        float s = 0.f;
        const float* pp = partial + (size_t)b * 56 * 256 + o;
#pragma unroll
        for (int r = seg * 14; r < seg * 14 + 14; ++r) s += pp[r * 256];
        rA[seg][o] = s;
    }
    __syncthreads();
    if (seg == 0) fc[o] = (rA[0][o] + rA[1][o] + rA[2][o] + rA[3][o]) * (1.f / 3136.f);
    __syncthreads();

    // stage2: f2 & v_c
    {
        float a2 = 0.f, av = 0.f;
        for (int i = i0; i < i0 + 64; ++i) {
            float fi = fc[i];
            a2 = fmaf(w01T[i * 256 + o], fi, a2);
            av = fmaf(fc1T[i * 256 + o], fi, av);
        }
        rA[seg][o] = a2; rB[seg][o] = av;
    }
    __syncthreads();
    if (seg == 0) {
        float A = rA[0][o] + rA[1][o] + rA[2][o] + rA[3][o];
        float V = rB[0][o] + rB[1][o] + rB[2][o] + rB[3][o];
        t2[o] = fmaxf(A + b0_1[o], 0.f) / (1.f + expf(-V));
    }
    __syncthreads();

    // stage3: f3
    {
        float a3 = 0.f;
        for (int i = i0; i < i0 + 64; ++i) a3 = fmaf(w02T[i * 256 + o], t2[i], a3);
        rA[seg][o] = a3;
    }
    __syncthreads();
    if (seg == 0) t3[o] = fmaxf(rA[0][o] + rA[1][o] + rA[2][o] + rA[3][o] + b0_2[o], 0.f);
    __syncthreads();

    // stage4: f4 (w03T) + f3s (w1T, 16-way split)
    {
        float a4 = 0.f;
        for (int i = i0; i < i0 + 64; ++i) a4 = fmaf(w03T[i * 256 + o], t3[i], a4);
        rA[seg][o] = a4;
        int o64 = tid & 63, s16 = tid >> 6;
        float a5 = 0.f;
        for (int i = s16 * 16; i < s16 * 16 + 16; ++i) a5 = fmaf(w1T[i * 64 + o64], t3[i], a5);
        ((float*)rB)[s16 * 64 + o64] = a5;
    }
    __syncthreads();
    if (seg == 0) t4[o] = fmaxf(rA[0][o] + rA[1][o] + rA[2][o] + rA[3][o] + b0_3[o], 0.f);
    if (tid < 64) {
        float a5 = 0.f;
        const float* rb = (const float*)rB;
#pragma unroll
        for (int j = 0; j < 16; ++j) a5 += rb[j * 64 + tid];
        float v = fmaxf(a5 + b1[tid], 0.f);
        red64[tid] = v * w2c[tid];
    }
    __syncthreads();
    if (tid == 0) {
        float u = 0.f;
        for (int i = 0; i < 64; ++i) u += red64[i];
        u = fmaxf(u + b2[0], 0.f);
        float c00 = compat[0], c01 = compat[1], c10 = compat[2], c11 = compat[3];
        float sw0 = spatial_w[0], sw1 = spatial_w[1];
        float q1 = 1.f / (1.f + expf(2.f * u));
        float q0 = 1.f - q1;
        for (int it = 0; it < 5; ++it) {
            float m0 = q0 * 0.25f * sw0;
            float m1 = q1 * 0.25f * sw1;
            float pw0 = c00 * m0 + c01 * m1;
            float pw1 = c10 * m0 + c11 * m1;
            float z0 = u - pw0, z1 = -u - pw1;
            q1 = 1.f / (1.f + expf(z0 - z1));
            q0 = 1.f - q1;
        }
        vs_sh = q1;
    }
    __syncthreads();

    // stage5: f_r then fc2
    {
        float a6 = 0.f;
        for (int i = i0; i < i0 + 64; ++i) a6 = fmaf(w04T[i * 256 + o], t4[i], a6);
        rA[seg][o] = a6;
    }
    __syncthreads();
    if (seg == 0) {
        float A = rA[0][o] + rA[1][o] + rA[2][o] + rA[3][o];
        float fr = fmaxf(vs_sh * A + b0_4[o], 0.f);
        rB[0][o] = fr * fc2_w[o];
    }
    __syncthreads();
    if (tid < 128) rB[0][tid] += rB[0][tid + 128];
    __syncthreads();
    if (tid < 64) rB[0][tid] += rB[0][tid + 64];
    __syncthreads();
    if (tid == 0) {
        float t = 0.f;
        for (int i = 0; i < 64; ++i) t += rB[0][i];
        out[b] = 1.f / (1.f + expf(-(t + fc2_b[0])));
    }
}

extern "C" void kernel_launch(void* const* d_in, const int* in_sizes, int n_in,
                              void* d_out, int out_size, void* d_ws, size_t ws_size,
                              hipStream_t stream) {
    const float* x     = (const float*)d_in[0];
    const float* w0_0  = (const float*)d_in[1];
    const float* b0_0  = (const float*)d_in[2];
    const float* w0_1  = (const float*)d_in[3];
    const float* b0_1  = (const float*)d_in[4];
    const float* w0_2  = (const float*)d_in[5];
    const float* b0_2  = (const float*)d_in[6];
    const float* w0_3  = (const float*)d_in[7];
    const float* b0_3  = (const float*)d_in[8];
    const float* w0_4  = (const float*)d_in[9];
    const float* b0_4  = (const float*)d_in[10];
    const float* w1    = (const float*)d_in[11];
    const float* b1    = (const float*)d_in[12];
    const float* w2    = (const float*)d_in[13];
    const float* b2    = (const float*)d_in[14];
    const float* fc1_w = (const float*)d_in[15];
    const float* fc2_w = (const float*)d_in[16];
    const float* fc2_b = (const float*)d_in[17];
    const float* compat = (const float*)d_in[18];
    const float* sw     = (const float*)d_in[19];

    unsigned short* xT = (unsigned short*)d_ws;
    unsigned short* Bp = xT + (size_t)128 * PPLANE * 32;
    float* w01T = (float*)(Bp + 589824);
    float* w02T = w01T + 65536;
    float* w03T = w02T + 65536;
    float* w04T = w03T + 65536;
    float* fc1T = w04T + 65536;
    float* w1T  = fc1T + 65536;
    float* w2c  = w1T + 16384;
    float* partial = w2c + 64;                                   // 16*56*256 f32

    hipLaunchKernelGGL(k_prep, dim3(NRX + NRW + NHALO), dim3(256), 0, stream,
                       x, w0_0, w0_1, w0_2, w0_3, w0_4, w1, w2, fc1_w,
                       xT, Bp, w01T, w02T, w03T, w04T, fc1T, w1T, w2c);
    hipLaunchKernelGGL(k_conv, dim3(896), dim3(256), 0, stream, xT, Bp, b0_0, partial);
    hipLaunchKernelGGL(k_tail, dim3(16), dim3(1024), 0, stream, partial,
                       w01T, fc1T, w02T, w03T, w04T, w1T, w2c,
                       b0_1, b0_2, b0_3, b0_4, b1, b2, fc2_w, fc2_b, compat, sw,
                       (float*)d_out);
}

// Round 6
// 201.754 us; speedup vs baseline: 1.2137x; 1.2137x over previous
//
#include <hip/hip_runtime.h>
#include <hip/hip_bf16.h>

typedef __bf16 bf16x8 __attribute__((ext_vector_type(8)));
typedef float f32x4 __attribute__((ext_vector_type(4)));

#define NB 16
#define NC 256
#define NHW 3136
#define NW 56
#define PROW 58
#define PPLANE (58 * 58)

#define NRX2 1568
#define NBP 288
#define NMAT 85
#define NHALO 114

__device__ __forceinline__ unsigned short f2bf(float f) {
    union { float f; unsigned u; } v; v.f = f;
    unsigned r = v.u + 0x7FFFu + ((v.u >> 16) & 1u);
    return (unsigned short)(r >> 16);
}

__device__ __forceinline__ void gload_lds16(const void* g, void* l) {
    __builtin_amdgcn_global_load_lds((const __attribute__((address_space(1))) void*)g,
                                     (__attribute__((address_space(3))) void*)l, 16, 0, 0);
}

// ---------- kernel 1: fused prep (fat blocks): repack_x || Bp || mats || halo ----------
__global__ void k_prep(const float* __restrict__ x,
                       const float* __restrict__ w0_0, const float* __restrict__ w0_1,
                       const float* __restrict__ w0_2, const float* __restrict__ w0_3,
                       const float* __restrict__ w0_4, const float* __restrict__ w1,
                       const float* __restrict__ w2, const float* __restrict__ fc1_w,
                       unsigned short* __restrict__ xT, unsigned short* __restrict__ Bp,
                       float* __restrict__ w01T, float* __restrict__ w02T,
                       float* __restrict__ w03T, float* __restrict__ w04T,
                       float* __restrict__ fc1T, float* __restrict__ w1T,
                       float* __restrict__ w2c) {
    __shared__ float sh[64 * 65];
    int bid = blockIdx.x, tid = threadIdx.x;

    if (bid < NRX2) {
        // ---- repack_x: 8 channel-block tiles per block ----
        int hwb = bid % 98;
        int b = bid / 98;
        int c_l = tid >> 5, hw_l = tid & 31;
        int qd = tid & 7, hw2 = tid >> 3;
        int hw = hwb * 32 + hw2;
        int y = hw / 56, xp = hw - y * 56;
        for (int cb = 0; cb < 8; ++cb) {
            const float* src = x + ((size_t)b * NC + (size_t)cb * 32) * NHW + hwb * 32;
#pragma unroll
            for (int r = 0; r < 4; ++r) {
                int c = c_l + r * 8;
                sh[c * 33 + hw_l] = src[(size_t)c * NHW + hw_l];
            }
            __syncthreads();
            unsigned short* dst = xT + ((size_t)(b * 8 + cb) * PPLANE +
                                        (size_t)(y + 1) * PROW + (xp + 1)) * 32 + qd * 4;
            ushort4 v;
            v.x = f2bf(sh[(qd * 4 + 0) * 33 + hw2]);
            v.y = f2bf(sh[(qd * 4 + 1) * 33 + hw2]);
            v.z = f2bf(sh[(qd * 4 + 2) * 33 + hw2]);
            v.w = f2bf(sh[(qd * 4 + 3) * 33 + hw2]);
            *(ushort4*)dst = v;
            __syncthreads();
        }
        return;
    }
    if (bid < NRX2 + NBP) {
        // ---- Bp repack: 2048 elements per block ----
        int bw = bid - NRX2;
#pragma unroll
        for (int k = 0; k < 8; ++k) {
            int idx = (bw * 8 + k) * 256 + tid;
            int q = idx & 31;
            int n = (idx >> 5) & 255;
            int s = idx >> 13;
            int tap = s >> 3;
            int ic = (s & 7) * 32 + q;
            Bp[idx] = f2bf(w0_0[(size_t)n * 2304 + (size_t)ic * 9 + tap]);
        }
        return;
    }
    if (bid < NRX2 + NBP + NMAT) {
        int tb = bid - NRX2 - NBP;
        if (tb < 84) {
            const float* src; float* dst;
            int sstr, estr, off, OD, o0, i0;
            if (tb < 80) {
                int arr = tb >> 4, t16 = tb & 15;
                o0 = (t16 >> 2) * 64; i0 = (t16 & 3) * 64; OD = 256;
                sstr = 2304; estr = 9; off = 4;
                switch (arr) {
                    case 0: src = w0_1; dst = w01T; break;
                    case 1: src = w0_2; dst = w02T; break;
                    case 2: src = w0_3; dst = w03T; break;
                    case 3: src = w0_4; dst = w04T; break;
                    default: src = fc1_w; dst = fc1T; sstr = 256; estr = 1; off = 0; break;
                }
            } else {
                int t4i = tb - 80; o0 = 0; i0 = t4i * 64; OD = 64;
                sstr = 2304; estr = 9; off = 4;
                src = w1; dst = w1T;
            }
            int i1 = tid & 63, o4 = tid >> 6;
#pragma unroll
            for (int p = 0; p < 16; ++p) {
                int oo = p * 4 + o4;
                sh[oo * 65 + i1] = src[(size_t)(o0 + oo) * sstr + (size_t)(i0 + i1) * estr + off];
            }
            __syncthreads();
            int o1 = tid & 63, i4 = tid >> 6;
#pragma unroll
            for (int p = 0; p < 16; ++p) {
                int ii = p * 4 + i4;
                dst[(size_t)(i0 + ii) * OD + o0 + o1] = sh[o1 * 65 + ii];
            }
        } else {
            if (tid < 64) w2c[tid] = w2[tid * 9 + 4];
        }
        return;
    }
    // ---- halo zero ----
    {
        int t = (bid - NRX2 - NBP - NMAT) * 256 + tid;
        if (t >= 128 * 228) return;
        int plane = t / 228, h = t % 228;
        int row, xc;
        if (h < 58)       { row = 0;       xc = h; }
        else if (h < 116) { row = 57;      xc = h - 58; }
        else if (h < 172) { row = h - 115; xc = 0; }
        else              { row = h - 171; xc = 57; }
        size_t e = ((size_t)plane * PPLANE + (size_t)row * PROW + xc) * 32;
        uint4 z = {0u, 0u, 0u, 0u};
        *(uint4*)(xT + e)      = z;
        *(uint4*)(xT + e + 8)  = z;
        *(uint4*)(xT + e + 16) = z;
        *(uint4*)(xT + e + 24) = z;
    }
}

// ---------- kernel 2: implicit-GEMM conv + relu + sum (R4 structure + B prefetch) ----------
// grid 448 (XCD-swizzled); 4 waves, wave owns 64 N cols. M = 112 flat px, K = 2304.
// A: per-icb LDS dbuf via global_load_lds (swizzled source, linear dest).
// B: direct from L2, software-pipelined one tap ahead in registers.
__global__ __launch_bounds__(256, 2) void k_conv(
    const unsigned short* __restrict__ xT,
    const unsigned short* __restrict__ Bp,
    const float* __restrict__ b0_0,
    float* __restrict__ partial) {
    __shared__ __align__(16) char alds[2][16384];   // [buf][4 rows][64 px][64B]
    int lblk = ((blockIdx.x & 7) * 56) + (blockIdx.x >> 3);  // bijective XCD swizzle
    int b = lblk / 28, pt = lblk % 28;
    int tid = threadIdx.x;
    int lane = tid & 63, wave = tid >> 6;
    int col = lane & 15, grp = lane >> 4;
    int nbase = wave * 64;

    // staging: per-lane swizzled global pixel offset (bytes)
    int swz = (lane & 3) ^ ((lane >> 3) & 3);
    int pixoff = ((lane >> 2) << 6) + (swz << 4);
    const char* xbytes = (const char*)xT;
    size_t stage_row = (size_t)(pt * 2 + wave) * (PROW * 64);

    // read-side LDS offsets: p_[mt][dx] (+ dyi*4096 per tap)
    int p_[7][3];
#pragma unroll
    for (int mt = 0; mt < 7; ++mt) {
        int q = mt * 16 + col;
        int r = q >= 56 ? 1 : 0;
        int x = q - 56 * r;
#pragma unroll
        for (int dxi = 0; dxi < 3; ++dxi) {
            int ppx = x + dxi;
            int slot = grp ^ ((ppx >> 1) & 3);
            p_[mt][dxi] = r * 4096 + ppx * 64 + slot * 16;
        }
    }
    int boff[4];
#pragma unroll
    for (int nt = 0; nt < 4; ++nt)
        boff[nt] = ((nbase + nt * 16 + col) * 32 + grp * 8) * 2;

    f32x4 acc[7][4];
#pragma unroll
    for (int mt = 0; mt < 7; ++mt)
#pragma unroll
        for (int nt = 0; nt < 4; ++nt) {
            acc[mt][nt][0] = 0.f; acc[mt][nt][1] = 0.f;
            acc[mt][nt][2] = 0.f; acc[mt][nt][3] = 0.f;
        }

    // prologue: stage icb=0 into buf0; preload B(tap0, icb0)
    {
        const char* g0 = xbytes + (size_t)(b * 8) * (PPLANE * 64) + stage_row + pixoff;
        char* l0 = &alds[0][wave * 4096];
#pragma unroll
        for (int j = 0; j < 4; ++j)
            gload_lds16(g0 + j * 1024, l0 + j * 1024);
    }
    bf16x8 bcur[4], bnxt[4];
    {
        const char* bp0 = (const char*)Bp;
#pragma unroll
        for (int nt = 0; nt < 4; ++nt)
            bcur[nt] = *(const bf16x8*)(bp0 + boff[nt]);
    }
    __syncthreads();

    for (int icb = 0; icb < 8; ++icb) {
        int cur = icb & 1;
        if (icb < 7) {
            const char* g = xbytes + (size_t)(b * 8 + icb + 1) * (PPLANE * 64) + stage_row + pixoff;
            char* l = &alds[cur ^ 1][wave * 4096];
#pragma unroll
            for (int j = 0; j < 4; ++j)
                gload_lds16(g + j * 1024, l + j * 1024);
        }
        const char* abuf = alds[cur];
#pragma unroll
        for (int tap = 0; tap < 9; ++tap) {
            // prefetch next phase's B into bnxt (one tap ahead, crosses icb boundary)
            int nicb = (tap == 8) ? icb + 1 : icb;
            int ntap = (tap == 8) ? 0 : tap + 1;
            if (nicb < 8) {
                const char* bp = (const char*)Bp + ((size_t)(ntap * 8 + nicb) << 13);
#pragma unroll
                for (int nt = 0; nt < 4; ++nt)
                    bnxt[nt] = *(const bf16x8*)(bp + boff[nt]);
            }
            int dyi = tap / 3, dxi = tap % 3;
            bf16x8 af[7];
#pragma unroll
            for (int mt = 0; mt < 7; ++mt)
                af[mt] = *(const bf16x8*)(abuf + (p_[mt][dxi] + dyi * 4096));
#pragma unroll
            for (int mt = 0; mt < 7; ++mt)
#pragma unroll
                for (int nt = 0; nt < 4; ++nt)
                    acc[mt][nt] = __builtin_amdgcn_mfma_f32_16x16x32_bf16(af[mt], bcur[nt], acc[mt][nt], 0, 0, 0);
#pragma unroll
            for (int nt = 0; nt < 4; ++nt) bcur[nt] = bnxt[nt];
        }
        __syncthreads();
    }

    // epilogue: bias + relu + sum over all 112 pixels
#pragma unroll
    for (int nt = 0; nt < 4; ++nt) {
        int n = nbase + nt * 16 + col;
        float bias = b0_0[n];
        float s = 0.f;
#pragma unroll
        for (int mt = 0; mt < 7; ++mt)
#pragma unroll
            for (int j = 0; j < 4; ++j)
                s += fmaxf(acc[mt][nt][j] + bias, 0.f);
        s += __shfl_down(s, 32);
        s += __shfl_down(s, 16);
        if (grp == 0) partial[(size_t)lblk * NC + n] = s;
    }
}

// ---------- kernel 3: tail, 1024 threads, 4-way K-split matvecs ----------
__global__ __launch_bounds__(1024) void k_tail(
    const float* __restrict__ partial,
    const float* __restrict__ w01T, const float* __restrict__ fc1T,
    const float* __restrict__ w02T, const float* __restrict__ w03T,
    const float* __restrict__ w04T, const float* __restrict__ w1T,
    const float* __restrict__ w2c,
    const float* __restrict__ b0_1, const float* __restrict__ b0_2,
    const float* __restrict__ b0_3, const float* __restrict__ b0_4,
    const float* __restrict__ b1, const float* __restrict__ b2,
    const float* __restrict__ fc2_w, const float* __restrict__ fc2_b,
    const float* __restrict__ compat, const float* __restrict__ spatial_w,
    float* __restrict__ out) {
    __shared__ float fc[256], t2[256], t3[256], t4[256];
    __shared__ float rA[4][256], rB[4][256];
    __shared__ float red64[64];
    __shared__ float vs_sh;
    int b = blockIdx.x, tid = threadIdx.x;
    int o = tid & 255, seg = tid >> 8;
    int i0 = seg * 64;

    // f1c mean: 28 per-tile partials, 7 per seg
    {
        float s = 0.f;
        const float* pp = partial + (size_t)b * 28 * 256 + o;
#pragma unroll
        for (int r = seg * 7; r < seg * 7 + 7; ++r) s += pp[r * 256];
        rA[seg][o] = s;
    }
    __syncthreads();
    if (seg == 0) fc[o] = (rA[0][o] + rA[1][o] + rA[2][o] + rA[3][o]) * (1.f / 3136.f);
    __syncthreads();

    // stage2: f2 & v_c
    {
        float a2 = 0.f, av = 0.f;
        for (int i = i0; i < i0 + 64; ++i) {
            float fi = fc[i];
            a2 = fmaf(w01T[i * 256 + o], fi, a2);
            av = fmaf(fc1T[i * 256 + o], fi, av);
        }
        rA[seg][o] = a2; rB[seg][o] = av;
    }
    __syncthreads();
    if (seg == 0) {
        float A = rA[0][o] + rA[1][o] + rA[2][o] + rA[3][o];
        float V = rB[0][o] + rB[1][o] + rB[2][o] + rB[3][o];
        t2[o] = fmaxf(A + b0_1[o], 0.f) / (1.f + expf(-V));
    }
    __syncthreads();

    // stage3: f3
    {
        float a3 = 0.f;
        for (int i = i0; i < i0 + 64; ++i) a3 = fmaf(w02T[i * 256 + o], t2[i], a3);
        rA[seg][o] = a3;
    }
    __syncthreads();
    if (seg == 0) t3[o] = fmaxf(rA[0][o] + rA[1][o] + rA[2][o] + rA[3][o] + b0_2[o], 0.f);
    __syncthreads();

    // stage4: f4 (w03T) + f3s (w1T, 16-way split)
    {
        float a4 = 0.f;
        for (int i = i0; i < i0 + 64; ++i) a4 = fmaf(w03T[i * 256 + o], t3[i], a4);
        rA[seg][o] = a4;
        int o64 = tid & 63, s16 = tid >> 6;
        float a5 = 0.f;
        for (int i = s16 * 16; i < s16 * 16 + 16; ++i) a5 = fmaf(w1T[i * 64 + o64], t3[i], a5);
        ((float*)rB)[s16 * 64 + o64] = a5;
    }
    __syncthreads();
    if (seg == 0) t4[o] = fmaxf(rA[0][o] + rA[1][o] + rA[2][o] + rA[3][o] + b0_3[o], 0.f);
    if (tid < 64) {
        float a5 = 0.f;
        const float* rb = (const float*)rB;
#pragma unroll
        for (int j = 0; j < 16; ++j) a5 += rb[j * 64 + tid];
        float v = fmaxf(a5 + b1[tid], 0.f);
        red64[tid] = v * w2c[tid];
    }
    __syncthreads();
    if (tid == 0) {
        float u = 0.f;
        for (int i = 0; i < 64; ++i) u += red64[i];
        u = fmaxf(u + b2[0], 0.f);
        float c00 = compat[0], c01 = compat[1], c10 = compat[2], c11 = compat[3];
        float sw0 = spatial_w[0], sw1 = spatial_w[1];
        float q1 = 1.f / (1.f + expf(2.f * u));
        float q0 = 1.f - q1;
        for (int it = 0; it < 5; ++it) {
            float m0 = q0 * 0.25f * sw0;
            float m1 = q1 * 0.25f * sw1;
            float pw0 = c00 * m0 + c01 * m1;
            float pw1 = c10 * m0 + c11 * m1;
            float z0 = u - pw0, z1 = -u - pw1;
            q1 = 1.f / (1.f + expf(z0 - z1));
            q0 = 1.f - q1;
        }
        vs_sh = q1;
    }
    __syncthreads();

    // stage5: f_r then fc2
    {
        float a6 = 0.f;
        for (int i = i0; i < i0 + 64; ++i) a6 = fmaf(w04T[i * 256 + o], t4[i], a6);
        rA[seg][o] = a6;
    }
    __syncthreads();
    if (seg == 0) {
        float A = rA[0][o] + rA[1][o] + rA[2][o] + rA[3][o];
        float fr = fmaxf(vs_sh * A + b0_4[o], 0.f);
        rB[0][o] = fr * fc2_w[o];
    }
    __syncthreads();
    if (tid < 128) rB[0][tid] += rB[0][tid + 128];
    __syncthreads();
    if (tid < 64) rB[0][tid] += rB[0][tid + 64];
    __syncthreads();
    if (tid == 0) {
        float t = 0.f;
        for (int i = 0; i < 64; ++i) t += rB[0][i];
        out[b] = 1.f / (1.f + expf(-(t + fc2_b[0])));
    }
}

extern "C" void kernel_launch(void* const* d_in, const int* in_sizes, int n_in,
                              void* d_out, int out_size, void* d_ws, size_t ws_size,
                              hipStream_t stream) {
    const float* x     = (const float*)d_in[0];
    const float* w0_0  = (const float*)d_in[1];
    const float* b0_0  = (const float*)d_in[2];
    const float* w0_1  = (const float*)d_in[3];
    const float* b0_1  = (const float*)d_in[4];
    const float* w0_2  = (const float*)d_in[5];
    const float* b0_2  = (const float*)d_in[6];
    const float* w0_3  = (const float*)d_in[7];
    const float* b0_3  = (const float*)d_in[8];
    const float* w0_4  = (const float*)d_in[9];
    const float* b0_4  = (const float*)d_in[10];
    const float* w1    = (const float*)d_in[11];
    const float* b1    = (const float*)d_in[12];
    const float* w2    = (const float*)d_in[13];
    const float* b2    = (const float*)d_in[14];
    const float* fc1_w = (const float*)d_in[15];
    const float* fc2_w = (const float*)d_in[16];
    const float* fc2_b = (const float*)d_in[17];
    const float* compat = (const float*)d_in[18];
    const float* sw     = (const float*)d_in[19];

    unsigned short* xT = (unsigned short*)d_ws;
    unsigned short* Bp = xT + (size_t)128 * PPLANE * 32;
    float* w01T = (float*)(Bp + 589824);
    float* w02T = w01T + 65536;
    float* w03T = w02T + 65536;
    float* w04T = w03T + 65536;
    float* fc1T = w04T + 65536;
    float* w1T  = fc1T + 65536;
    float* w2c  = w1T + 16384;
    float* partial = w2c + 64;                                   // 448*256 f32

    hipLaunchKernelGGL(k_prep, dim3(NRX2 + NBP + NMAT + NHALO), dim3(256), 0, stream,
                       x, w0_0, w0_1, w0_2, w0_3, w0_4, w1, w2, fc1_w,
                       xT, Bp, w01T, w02T, w03T, w04T, fc1T, w1T, w2c);
    hipLaunchKernelGGL(k_conv, dim3(448), dim3(256), 0, stream, xT, Bp, b0_0, partial);
    hipLaunchKernelGGL(k_tail, dim3(16), dim3(1024), 0, stream, partial,
                       w01T, fc1T, w02T, w03T, w04T, w1T, w2c,
                       b0_1, b0_2, b0_3, b0_4, b1, b2, fc2_w, fc2_b, compat, sw,
                       (float*)d_out);
}

// Round 7
// 196.706 us; speedup vs baseline: 1.2448x; 1.0257x over previous
//
#include <hip/hip_runtime.h>
#include <hip/hip_bf16.h>

typedef __bf16 bf16x8 __attribute__((ext_vector_type(8)));
typedef float f32x4 __attribute__((ext_vector_type(4)));

#define NB 16
#define NC 256
#define NHW 3136
#define NW 56
#define PROW 58
#define PPLANE (58 * 58)

#define NRX 12544
#define NRW 2389
#define NHALO 114

__device__ __forceinline__ unsigned short f2bf(float f) {
    union { float f; unsigned u; } v; v.f = f;
    unsigned r = v.u + 0x7FFFu + ((v.u >> 16) & 1u);
    return (unsigned short)(r >> 16);
}

__device__ __forceinline__ void gload_lds16(const void* g, void* l) {
    __builtin_amdgcn_global_load_lds((const __attribute__((address_space(1))) void*)g,
                                     (__attribute__((address_space(3))) void*)l, 16, 0, 0);
}

// ---------- kernel 1: fused prep (THIN blocks): repack_x || Bp+mats || halo ----------
__global__ void k_prep(const float* __restrict__ x,
                       const float* __restrict__ w0_0, const float* __restrict__ w0_1,
                       const float* __restrict__ w0_2, const float* __restrict__ w0_3,
                       const float* __restrict__ w0_4, const float* __restrict__ w1,
                       const float* __restrict__ w2, const float* __restrict__ fc1_w,
                       unsigned short* __restrict__ xT, unsigned short* __restrict__ Bp,
                       float* __restrict__ w01T, float* __restrict__ w02T,
                       float* __restrict__ w03T, float* __restrict__ w04T,
                       float* __restrict__ fc1T, float* __restrict__ w1T,
                       float* __restrict__ w2c) {
    __shared__ float sh[64 * 65];
    int bid = blockIdx.x, tid = threadIdx.x;

    if (bid < NRX) {
        // ---- repack_x: NCHW f32 -> padded channel-blocked bf16 ----
        int hwb = bid % 98;
        int cb = (bid / 98) % 8;
        int b = bid / (98 * 8);
        {
            int c_l = tid >> 5, hw_l = tid & 31;
            const float* src = x + ((size_t)b * NC + (size_t)cb * 32) * NHW + hwb * 32;
#pragma unroll
            for (int r = 0; r < 4; ++r) {
                int c = c_l + r * 8;
                sh[c * 33 + hw_l] = src[(size_t)c * NHW + hw_l];
            }
        }
        __syncthreads();
        {
            int qd = tid & 7, hw2 = tid >> 3;
            int hw = hwb * 32 + hw2;
            int y = hw / 56, xp = hw - y * 56;
            unsigned short* dst = xT + ((size_t)(b * 8 + cb) * PPLANE +
                                        (size_t)(y + 1) * PROW + (xp + 1)) * 32 + qd * 4;
            ushort4 v;
            v.x = f2bf(sh[(qd * 4 + 0) * 33 + hw2]);
            v.y = f2bf(sh[(qd * 4 + 1) * 33 + hw2]);
            v.z = f2bf(sh[(qd * 4 + 2) * 33 + hw2]);
            v.w = f2bf(sh[(qd * 4 + 3) * 33 + hw2]);
            *(ushort4*)dst = v;
        }
        return;
    }
    if (bid < NRX + NRW) {
        int bw = bid - NRX;
        if (bw < 2304) {
            int idx = bw * 256 + tid;
            int q = idx & 31;
            int n = (idx >> 5) & 255;
            int s = idx >> 13;
            int tap = s >> 3;
            int ic = (s & 7) * 32 + q;
            Bp[idx] = f2bf(w0_0[(size_t)n * 2304 + (size_t)ic * 9 + tap]);
            return;
        }
        int tb = bw - 2304;
        if (tb < 84) {
            const float* src; float* dst;
            int sstr, estr, off, OD, o0, i0;
            if (tb < 80) {
                int arr = tb >> 4, t16 = tb & 15;
                o0 = (t16 >> 2) * 64; i0 = (t16 & 3) * 64; OD = 256;
                sstr = 2304; estr = 9; off = 4;
                switch (arr) {
                    case 0: src = w0_1; dst = w01T; break;
                    case 1: src = w0_2; dst = w02T; break;
                    case 2: src = w0_3; dst = w03T; break;
                    case 3: src = w0_4; dst = w04T; break;
                    default: src = fc1_w; dst = fc1T; sstr = 256; estr = 1; off = 0; break;
                }
            } else {
                int t4i = tb - 80; o0 = 0; i0 = t4i * 64; OD = 64;
                sstr = 2304; estr = 9; off = 4;
                src = w1; dst = w1T;
            }
            int i1 = tid & 63, o4 = tid >> 6;
#pragma unroll
            for (int p = 0; p < 16; ++p) {
                int oo = p * 4 + o4;
                sh[oo * 65 + i1] = src[(size_t)(o0 + oo) * sstr + (size_t)(i0 + i1) * estr + off];
            }
            __syncthreads();
            int o1 = tid & 63, i4 = tid >> 6;
#pragma unroll
            for (int p = 0; p < 16; ++p) {
                int ii = p * 4 + i4;
                dst[(size_t)(i0 + ii) * OD + o0 + o1] = sh[o1 * 65 + ii];
            }
        } else {
            if (tid < 64) w2c[tid] = w2[tid * 9 + 4];
        }
        return;
    }
    // ---- halo zero ----
    {
        int t = (bid - NRX - NRW) * 256 + tid;
        if (t >= 128 * 228) return;
        int plane = t / 228, h = t % 228;
        int row, xc;
        if (h < 58)       { row = 0;       xc = h; }
        else if (h < 116) { row = 57;      xc = h - 58; }
        else if (h < 172) { row = h - 115; xc = 0; }
        else              { row = h - 171; xc = 57; }
        size_t e = ((size_t)plane * PPLANE + (size_t)row * PROW + xc) * 32;
        uint4 z = {0u, 0u, 0u, 0u};
        *(uint4*)(xT + e)      = z;
        *(uint4*)(xT + e + 8)  = z;
        *(uint4*)(xT + e + 16) = z;
        *(uint4*)(xT + e + 24) = z;
    }
}

// ---------- kernel 2: implicit-GEMM conv + relu + sum ----------
// grid 448 (XCD-swizzled); 4 waves, wave owns 64 N cols. M = 112 flat px, K = 2304.
// A: per-icb LDS dbuf via global_load_lds (swizzled source, linear dest).
// B: direct from L2, depth-2 tap-ahead register ring (covers ~300cy L2 latency).
__global__ __launch_bounds__(256, 2) void k_conv(
    const unsigned short* __restrict__ xT,
    const unsigned short* __restrict__ Bp,
    const float* __restrict__ b0_0,
    float* __restrict__ partial) {
    __shared__ __align__(16) char alds[2][16384];   // [buf][4 rows][64 px][64B]
    int lblk = ((blockIdx.x & 7) * 56) + (blockIdx.x >> 3);  // bijective XCD swizzle
    int b = lblk / 28, pt = lblk % 28;
    int tid = threadIdx.x;
    int lane = tid & 63, wave = tid >> 6;
    int col = lane & 15, grp = lane >> 4;
    int nbase = wave * 64;

    // staging: per-lane swizzled global pixel offset (bytes)
    int swz = (lane & 3) ^ ((lane >> 3) & 3);
    int pixoff = ((lane >> 2) << 6) + (swz << 4);
    const char* xbytes = (const char*)xT;
    size_t stage_row = (size_t)(pt * 2 + wave) * (PROW * 64);

    // read-side LDS offsets: p_[mt][dx] (+ dyi*4096 per tap)
    int p_[7][3];
#pragma unroll
    for (int mt = 0; mt < 7; ++mt) {
        int q = mt * 16 + col;
        int r = q >= 56 ? 1 : 0;
        int x = q - 56 * r;
#pragma unroll
        for (int dxi = 0; dxi < 3; ++dxi) {
            int ppx = x + dxi;
            int slot = grp ^ ((ppx >> 1) & 3);
            p_[mt][dxi] = r * 4096 + ppx * 64 + slot * 16;
        }
    }
    int boff[4];
#pragma unroll
    for (int nt = 0; nt < 4; ++nt)
        boff[nt] = ((nbase + nt * 16 + col) * 32 + grp * 8) * 2;

    f32x4 acc[7][4];
#pragma unroll
    for (int mt = 0; mt < 7; ++mt)
#pragma unroll
        for (int nt = 0; nt < 4; ++nt) {
            acc[mt][nt][0] = 0.f; acc[mt][nt][1] = 0.f;
            acc[mt][nt][2] = 0.f; acc[mt][nt][3] = 0.f;
        }

    // prologue: stage icb=0 into buf0; preload B for global taps 0 and 1
    {
        const char* g0 = xbytes + (size_t)(b * 8) * (PPLANE * 64) + stage_row + pixoff;
        char* l0 = &alds[0][wave * 4096];
#pragma unroll
        for (int j = 0; j < 4; ++j)
            gload_lds16(g0 + j * 1024, l0 + j * 1024);
    }
    bf16x8 bq[3][4];
    {
        const char* bp0 = (const char*)Bp;                         // tap0, icb0
        const char* bp1 = (const char*)Bp + ((size_t)(1 * 8) << 13); // tap1, icb0
#pragma unroll
        for (int nt = 0; nt < 4; ++nt) {
            bq[0][nt] = *(const bf16x8*)(bp0 + boff[nt]);
            bq[1][nt] = *(const bf16x8*)(bp1 + boff[nt]);
        }
    }
    __syncthreads();

    for (int icb = 0; icb < 8; ++icb) {
        int cur = icb & 1;
        if (icb < 7) {
            const char* g = xbytes + (size_t)(b * 8 + icb + 1) * (PPLANE * 64) + stage_row + pixoff;
            char* l = &alds[cur ^ 1][wave * 4096];
#pragma unroll
            for (int j = 0; j < 4; ++j)
                gload_lds16(g + j * 1024, l + j * 1024);
        }
        const char* abuf = alds[cur];
#pragma unroll
        for (int tap = 0; tap < 9; ++tap) {
            // prefetch B for global tap g+2 into bq[(tap+2)%3]
            {
                int gt = tap + 2;
                int nicb = icb + (gt >= 9 ? 1 : 0);
                int ntap = gt >= 9 ? gt - 9 : gt;
                if (nicb < 8) {
                    const char* bp = (const char*)Bp + ((size_t)(ntap * 8 + nicb) << 13);
#pragma unroll
                    for (int nt = 0; nt < 4; ++nt)
                        bq[(tap + 2) % 3][nt] = *(const bf16x8*)(bp + boff[nt]);
                }
            }
            int dyi = tap / 3, dxi = tap % 3;
            bf16x8 af[7];
#pragma unroll
            for (int mt = 0; mt < 7; ++mt)
                af[mt] = *(const bf16x8*)(abuf + (p_[mt][dxi] + dyi * 4096));
            __builtin_amdgcn_s_setprio(1);
#pragma unroll
            for (int mt = 0; mt < 7; ++mt)
#pragma unroll
                for (int nt = 0; nt < 4; ++nt)
                    acc[mt][nt] = __builtin_amdgcn_mfma_f32_16x16x32_bf16(af[mt], bq[tap % 3][nt], acc[mt][nt], 0, 0, 0);
            __builtin_amdgcn_s_setprio(0);
        }
        __syncthreads();
    }

    // epilogue: bias + relu + sum over all 112 pixels
#pragma unroll
    for (int nt = 0; nt < 4; ++nt) {
        int n = nbase + nt * 16 + col;
        float bias = b0_0[n];
        float s = 0.f;
#pragma unroll
        for (int mt = 0; mt < 7; ++mt)
#pragma unroll
            for (int j = 0; j < 4; ++j)
                s += fmaxf(acc[mt][nt][j] + bias, 0.f);
        s += __shfl_down(s, 32);
        s += __shfl_down(s, 16);
        if (grp == 0) partial[(size_t)lblk * NC + n] = s;
    }
}

// ---------- kernel 3: tail, 1024 threads, 4-way K-split matvecs ----------
__global__ __launch_bounds__(1024) void k_tail(
    const float* __restrict__ partial,
    const float* __restrict__ w01T, const float* __restrict__ fc1T,
    const float* __restrict__ w02T, const float* __restrict__ w03T,
    const float* __restrict__ w04T, const float* __restrict__ w1T,
    const float* __restrict__ w2c,
    const float* __restrict__ b0_1, const float* __restrict__ b0_2,
    const float* __restrict__ b0_3, const float* __restrict__ b0_4,
    const float* __restrict__ b1, const float* __restrict__ b2,
    const float* __restrict__ fc2_w, const float* __restrict__ fc2_b,
    const float* __restrict__ compat, const float* __restrict__ spatial_w,
    float* __restrict__ out) {
    __shared__ float fc[256], t2[256], t3[256], t4[256];
    __shared__ float rA[4][256], rB[4][256];
    __shared__ float red64[64];
    __shared__ float vs_sh;
    int b = blockIdx.x, tid = threadIdx.x;
    int o = tid & 255, seg = tid >> 8;
    int i0 = seg * 64;

    // f1c mean: 28 per-tile partials, 7 per seg
    {
        float s = 0.f;
        const float* pp = partial + (size_t)b * 28 * 256 + o;
#pragma unroll
        for (int r = seg * 7; r < seg * 7 + 7; ++r) s += pp[r * 256];
        rA[seg][o] = s;
    }
    __syncthreads();
    if (seg == 0) fc[o] = (rA[0][o] + rA[1][o] + rA[2][o] + rA[3][o]) * (1.f / 3136.f);
    __syncthreads();

    // stage2: f2 & v_c
    {
        float a2 = 0.f, av = 0.f;
        for (int i = i0; i < i0 + 64; ++i) {
            float fi = fc[i];
            a2 = fmaf(w01T[i * 256 + o], fi, a2);
            av = fmaf(fc1T[i * 256 + o], fi, av);
        }
        rA[seg][o] = a2; rB[seg][o] = av;
    }
    __syncthreads();
    if (seg == 0) {
        float A = rA[0][o] + rA[1][o] + rA[2][o] + rA[3][o];
        float V = rB[0][o] + rB[1][o] + rB[2][o] + rB[3][o];
        t2[o] = fmaxf(A + b0_1[o], 0.f) / (1.f + expf(-V));
    }
    __syncthreads();

    // stage3: f3
    {
        float a3 = 0.f;
        for (int i = i0; i < i0 + 64; ++i) a3 = fmaf(w02T[i * 256 + o], t2[i], a3);
        rA[seg][o] = a3;
    }
    __syncthreads();
    if (seg == 0) t3[o] = fmaxf(rA[0][o] + rA[1][o] + rA[2][o] + rA[3][o] + b0_2[o], 0.f);
    __syncthreads();

    // stage4: f4 (w03T) + f3s (w1T, 16-way split)
    {
        float a4 = 0.f;
        for (int i = i0; i < i0 + 64; ++i) a4 = fmaf(w03T[i * 256 + o], t3[i], a4);
        rA[seg][o] = a4;
        int o64 = tid & 63, s16 = tid >> 6;
        float a5 = 0.f;
        for (int i = s16 * 16; i < s16 * 16 + 16; ++i) a5 = fmaf(w1T[i * 64 + o64], t3[i], a5);
        ((float*)rB)[s16 * 64 + o64] = a5;
    }
    __syncthreads();
    if (seg == 0) t4[o] = fmaxf(rA[0][o] + rA[1][o] + rA[2][o] + rA[3][o] + b0_3[o], 0.f);
    if (tid < 64) {
        float a5 = 0.f;
        const float* rb = (const float*)rB;
#pragma unroll
        for (int j = 0; j < 16; ++j) a5 += rb[j * 64 + tid];
        float v = fmaxf(a5 + b1[tid], 0.f);
        red64[tid] = v * w2c[tid];
    }
    __syncthreads();
    if (tid == 0) {
        float u = 0.f;
        for (int i = 0; i < 64; ++i) u += red64[i];
        u = fmaxf(u + b2[0], 0.f);
        float c00 = compat[0], c01 = compat[1], c10 = compat[2], c11 = compat[3];
        float sw0 = spatial_w[0], sw1 = spatial_w[1];
        float q1 = 1.f / (1.f + expf(2.f * u));
        float q0 = 1.f - q1;
        for (int it = 0; it < 5; ++it) {
            float m0 = q0 * 0.25f * sw0;
            float m1 = q1 * 0.25f * sw1;
            float pw0 = c00 * m0 + c01 * m1;
            float pw1 = c10 * m0 + c11 * m1;
            float z0 = u - pw0, z1 = -u - pw1;
            q1 = 1.f / (1.f + expf(z0 - z1));
            q0 = 1.f - q1;
        }
        vs_sh = q1;
    }
    __syncthreads();

    // stage5: f_r then fc2
    {
        float a6 = 0.f;
        for (int i = i0; i < i0 + 64; ++i) a6 = fmaf(w04T[i * 256 + o], t4[i], a6);
        rA[seg][o] = a6;
    }
    __syncthreads();
    if (seg == 0) {
        float A = rA[0][o] + rA[1][o] + rA[2][o] + rA[3][o];
        float fr = fmaxf(vs_sh * A + b0_4[o], 0.f);
        rB[0][o] = fr * fc2_w[o];
    }
    __syncthreads();
    if (tid < 128) rB[0][tid] += rB[0][tid + 128];
    __syncthreads();
    if (tid < 64) rB[0][tid] += rB[0][tid + 64];
    __syncthreads();
    if (tid == 0) {
        float t = 0.f;
        for (int i = 0; i < 64; ++i) t += rB[0][i];
        out[b] = 1.f / (1.f + expf(-(t + fc2_b[0])));
    }
}

extern "C" void kernel_launch(void* const* d_in, const int* in_sizes, int n_in,
                              void* d_out, int out_size, void* d_ws, size_t ws_size,
                              hipStream_t stream) {
    const float* x     = (const float*)d_in[0];
    const float* w0_0  = (const float*)d_in[1];
    const float* b0_0  = (const float*)d_in[2];
    const float* w0_1  = (const float*)d_in[3];
    const float* b0_1  = (const float*)d_in[4];
    const float* w0_2  = (const float*)d_in[5];
    const float* b0_2  = (const float*)d_in[6];
    const float* w0_3  = (const float*)d_in[7];
    const float* b0_3  = (const float*)d_in[8];
    const float* w0_4  = (const float*)d_in[9];
    const float* b0_4  = (const float*)d_in[10];
    const float* w1    = (const float*)d_in[11];
    const float* b1    = (const float*)d_in[12];
    const float* w2    = (const float*)d_in[13];
    const float* b2    = (const float*)d_in[14];
    const float* fc1_w = (const float*)d_in[15];
    const float* fc2_w = (const float*)d_in[16];
    const float* fc2_b = (const float*)d_in[17];
    const float* compat = (const float*)d_in[18];
    const float* sw     = (const float*)d_in[19];

    unsigned short* xT = (unsigned short*)d_ws;
    unsigned short* Bp = xT + (size_t)128 * PPLANE * 32;
    float* w01T = (float*)(Bp + 589824);
    float* w02T = w01T + 65536;
    float* w03T = w02T + 65536;
    float* w04T = w03T + 65536;
    float* fc1T = w04T + 65536;
    float* w1T  = fc1T + 65536;
    float* w2c  = w1T + 16384;
    float* partial = w2c + 64;                                   // 448*256 f32

    hipLaunchKernelGGL(k_prep, dim3(NRX + NRW + NHALO), dim3(256), 0, stream,
                       x, w0_0, w0_1, w0_2, w0_3, w0_4, w1, w2, fc1_w,
                       xT, Bp, w01T, w02T, w03T, w04T, fc1T, w1T, w2c);
    hipLaunchKernelGGL(k_conv, dim3(448), dim3(256), 0, stream, xT, Bp, b0_0, partial);
    hipLaunchKernelGGL(k_tail, dim3(16), dim3(1024), 0, stream, partial,
                       w01T, fc1T, w02T, w03T, w04T, w1T, w2c,
                       b0_1, b0_2, b0_3, b0_4, b1, b2, fc2_w, fc2_b, compat, sw,
                       (float*)d_out);
}